// Round 2
// baseline (775.815 us; speedup 1.0000x reference)
//
#include <hip/hip_runtime.h>
#include <hip/hip_bf16.h>

#define S_LEN   2048
#define D_MODEL 1024
#define NH      16
#define DK      64
#define BATCH   2
#define M_ROWS  (BATCH * S_LEN)   // 4096

// ---------------------------------------------------------------------------
// GEMM (B-transposed): C[m, n] = sum_k A[m,k] * W[n,k], K = 1024 fixed.
// W is selected from {W0,W1,W2} by n-range of 1024 (lets one kernel do the
// fused QKV projection with 3 separate weight pointers).
// 64x64 tile, BK=16, 256 threads, 4x4 microtile, fp32 VALU.
// ---------------------------------------------------------------------------
__global__ __launch_bounds__(256) void gemm_bt(const float* __restrict__ A,
                                               const float* __restrict__ W0,
                                               const float* __restrict__ W1,
                                               const float* __restrict__ W2,
                                               float* __restrict__ C, int N) {
    __shared__ float As[16][64];   // [k][m] transposed for float4 fragment reads
    __shared__ float Bs[16][64];   // [k][n]

    const int tid = threadIdx.x;
    const int tx = tid & 15;        // n-subtile
    const int ty = tid >> 4;        // m-subtile
    const int m0 = blockIdx.y * 64;
    const int n0 = blockIdx.x * 64;

    const float* W = (n0 < 1024) ? W0 : (n0 < 2048 ? W1 : W2);
    const int nb = n0 & 1023;

    const int lr = tid >> 2;          // 0..63: row within tile for staging
    const int lc = (tid & 3) << 2;    // 0,4,8,12: col (k) offset for staging

    const float* Arow = A + (size_t)(m0 + lr) * D_MODEL + lc;
    const float* Wrow = W + (size_t)(nb + lr) * D_MODEL + lc;

    float acc[4][4] = {{0.f}};

    for (int k0 = 0; k0 < D_MODEL; k0 += 16) {
        __syncthreads();
        float4 av = *(const float4*)(Arow + k0);
        float4 bv = *(const float4*)(Wrow + k0);
        As[lc + 0][lr] = av.x; As[lc + 1][lr] = av.y;
        As[lc + 2][lr] = av.z; As[lc + 3][lr] = av.w;
        Bs[lc + 0][lr] = bv.x; Bs[lc + 1][lr] = bv.y;
        Bs[lc + 2][lr] = bv.z; Bs[lc + 3][lr] = bv.w;
        __syncthreads();
#pragma unroll
        for (int kk = 0; kk < 16; ++kk) {
            float a[4], b[4];
            *(float4*)a = *(const float4*)&As[kk][ty << 2];
            *(float4*)b = *(const float4*)&Bs[kk][tx << 2];
#pragma unroll
            for (int i = 0; i < 4; ++i)
#pragma unroll
                for (int j = 0; j < 4; ++j)
                    acc[i][j] += a[i] * b[j];
        }
    }

#pragma unroll
    for (int i = 0; i < 4; ++i) {
        float* Crow = C + (size_t)(m0 + (ty << 2) + i) * N + n0 + (tx << 2);
        *(float4*)Crow = make_float4(acc[i][0], acc[i][1], acc[i][2], acc[i][3]);
    }
}

// ---------------------------------------------------------------------------
// Sliding-window ALiBi attention, fp32.
// qkv: [M_ROWS, 3072] rows = (b*S + s); cols [0,1024)=Q, [1024,2048)=K, [2048,3072)=V,
//      each split per-head as h*64 + d.
// One block per (64-query tile, head, batch). K/V processed in 32-row chunks
// spanning [q0-128, q0+192): 10 chunks. Online softmax (-1e30 sentinel).
// Thread (tx,ty): queries 4*ty..+3; scores cols 2*tx..+1 per chunk; out cols 4*tx..+3.
// ---------------------------------------------------------------------------
__global__ __launch_bounds__(256) void attn_win(const float* __restrict__ qkv,
                                                const float* __restrict__ slopes,
                                                float* __restrict__ aout) {
    __shared__ float Qs[64][65];
    __shared__ float Ks[32][65];
    __shared__ float Vs[32][65];
    __shared__ float Ps[64][33];

    const int tid = threadIdx.x;
    const int tx = tid & 15;
    const int ty = tid >> 4;
    const int q0 = blockIdx.x * 64;
    const int h  = blockIdx.y;
    const int b  = blockIdx.z;
    const float slope = slopes[h];
    const size_t rowbase = (size_t)b * S_LEN * 3072;

    // Stage Q tile: 64 rows x 64 cols = 1024 float4s; 4 per thread.
    // (Round-0 bug: only 1 float4/thread was staged -> cols 16..63 were stale LDS.)
#pragma unroll
    for (int e = 0; e < 4; ++e) {
        int idx = e * 256 + tid;          // 0..1023
        int r = idx >> 4;                 // 0..63
        int c = (idx & 15) << 2;          // 0..60
        float4 v = *(const float4*)(qkv + rowbase + (size_t)(q0 + r) * 3072 + h * DK + c);
        Qs[r][c + 0] = v.x; Qs[r][c + 1] = v.y; Qs[r][c + 2] = v.z; Qs[r][c + 3] = v.w;
    }

    float m_i[4], l_i[4], o[4][4];
#pragma unroll
    for (int i = 0; i < 4; ++i) {
        m_i[i] = -1e30f; l_i[i] = 0.f;
#pragma unroll
        for (int j = 0; j < 4; ++j) o[i][j] = 0.f;
    }

    for (int c = 0; c < 10; ++c) {
        const int k0 = q0 - 128 + c * 32;
        __syncthreads();   // previous chunk's Ks/Vs/Ps reads done; also fences Qs writes (c==0)
        // Stage K/V chunk: 32 rows x 64 cols each; 2 float4 per thread.
#pragma unroll
        for (int e = 0; e < 2; ++e) {
            int idx = e * 256 + tid;          // 0..511
            int r = idx >> 4;                 // 0..31
            int cc = (idx & 15) << 2;         // 0..60
            int kpos = k0 + r;
            float4 kv = make_float4(0.f, 0.f, 0.f, 0.f);
            float4 vv = make_float4(0.f, 0.f, 0.f, 0.f);
            if (kpos >= 0 && kpos < S_LEN) {
                const float* kp = qkv + rowbase + (size_t)kpos * 3072 + 1024 + h * DK + cc;
                kv = *(const float4*)kp;
                vv = *(const float4*)(kp + 1024);
            }
            Ks[r][cc + 0] = kv.x; Ks[r][cc + 1] = kv.y; Ks[r][cc + 2] = kv.z; Ks[r][cc + 3] = kv.w;
            Vs[r][cc + 0] = vv.x; Vs[r][cc + 1] = vv.y; Vs[r][cc + 2] = vv.z; Vs[r][cc + 3] = vv.w;
        }
        __syncthreads();

        // Scores: 4 queries x 2 keys per thread.
        float s[4][2] = {{0.f}};
        for (int dd = 0; dd < 64; ++dd) {
            float qv[4], kv[2];
#pragma unroll
            for (int i = 0; i < 4; ++i) qv[i] = Qs[(ty << 2) + i][dd];
#pragma unroll
            for (int j = 0; j < 2; ++j) kv[j] = Ks[(tx << 1) + j][dd];
#pragma unroll
            for (int i = 0; i < 4; ++i)
#pragma unroll
                for (int j = 0; j < 2; ++j)
                    s[i][j] += qv[i] * kv[j];
        }

        // Bias + mask + online softmax update.
#pragma unroll
        for (int i = 0; i < 4; ++i) {
            const int qpos = q0 + (ty << 2) + i;
            float mx = -1e30f;
#pragma unroll
            for (int j = 0; j < 2; ++j) {
                const int kpos = k0 + (tx << 1) + j;
                const int rel = qpos - kpos;
                const bool ok = (kpos >= 0) && (kpos < S_LEN) && (rel <= 128) && (rel >= -128);
                s[i][j] = ok ? (s[i][j] * 0.125f + slope * (float)rel) : -1e30f;
                mx = fmaxf(mx, s[i][j]);
            }
#pragma unroll
            for (int off = 1; off < 16; off <<= 1) mx = fmaxf(mx, __shfl_xor(mx, off, 64));
            const float mnew = fmaxf(m_i[i], mx);
            const float alpha = __expf(m_i[i] - mnew);   // harmless 1.0 when both -1e30 (l=o=0)
            float psum = 0.f;
#pragma unroll
            for (int j = 0; j < 2; ++j) {
                float p = __expf(s[i][j] - mnew);
                if (s[i][j] < -9e29f) p = 0.f;           // fully-masked guard
                s[i][j] = p;
                psum += p;
            }
#pragma unroll
            for (int off = 1; off < 16; off <<= 1) psum += __shfl_xor(psum, off, 64);
            l_i[i] = l_i[i] * alpha + psum;
            m_i[i] = mnew;
#pragma unroll
            for (int j = 0; j < 4; ++j) o[i][j] *= alpha;
#pragma unroll
            for (int j = 0; j < 2; ++j) Ps[(ty << 2) + i][(tx << 1) + j] = s[i][j];
        }
        __syncthreads();

        // PV accumulate: o[i][j] += sum_kk Ps[qi][kk] * Vs[kk][4*tx+j]
        for (int kk = 0; kk < 32; ++kk) {
            float pv[4], vv[4];
#pragma unroll
            for (int i = 0; i < 4; ++i) pv[i] = Ps[(ty << 2) + i][kk];
#pragma unroll
            for (int j = 0; j < 4; ++j) vv[j] = Vs[kk][(tx << 2) + j];
#pragma unroll
            for (int i = 0; i < 4; ++i)
#pragma unroll
                for (int j = 0; j < 4; ++j)
                    o[i][j] += pv[i] * vv[j];
        }
    }

    // Epilogue: divide by l, write [B,S,D] with col h*64 + 4*tx + j.
#pragma unroll
    for (int i = 0; i < 4; ++i) {
        const int qpos = q0 + (ty << 2) + i;
        const float inv = 1.f / l_i[i];
        float* dst = aout + ((size_t)b * S_LEN + qpos) * D_MODEL + h * DK + (tx << 2);
        *(float4*)dst = make_float4(o[i][0] * inv, o[i][1] * inv, o[i][2] * inv, o[i][3] * inv);
    }
}

// ---------------------------------------------------------------------------
extern "C" void kernel_launch(void* const* d_in, const int* in_sizes, int n_in,
                              void* d_out, int out_size, void* d_ws, size_t ws_size,
                              hipStream_t stream) {
    const float* x      = (const float*)d_in[0];
    const float* Wq     = (const float*)d_in[1];
    const float* Wk     = (const float*)d_in[2];
    const float* Wv     = (const float*)d_in[3];
    const float* Wo     = (const float*)d_in[4];
    const float* slopes = (const float*)d_in[5];
    float* out = (float*)d_out;

    float* qkv  = (float*)d_ws;                       // [4096, 3072]
    float* aout = qkv + (size_t)M_ROWS * 3072;        // [4096, 1024]
    // ws needed: (4096*3072 + 4096*1024) * 4 B = 64 MiB

    dim3 blk(256);
    // 1) fused QKV projection
    gemm_bt<<<dim3(3072 / 64, M_ROWS / 64), blk, 0, stream>>>(x, Wq, Wk, Wv, qkv, 3072);
    // 2) windowed ALiBi attention
    attn_win<<<dim3(S_LEN / 64, NH, BATCH), blk, 0, stream>>>(qkv, slopes, aout);
    // 3) output projection
    gemm_bt<<<dim3(1024 / 64, M_ROWS / 64), blk, 0, stream>>>(aout, Wo, Wo, Wo, out, 1024);
}

// Round 3
// 380.939 us; speedup vs baseline: 2.0366x; 2.0366x over previous
//
#include <hip/hip_runtime.h>
#include <hip/hip_bf16.h>

#define S_LEN   2048
#define D_MODEL 1024
#define NH      16
#define DK      64
#define BATCH   2
#define M_ROWS  (BATCH * S_LEN)   // 4096

typedef __attribute__((ext_vector_type(8))) short bf16x8;
typedef __attribute__((ext_vector_type(4))) float f32x4;
typedef __attribute__((ext_vector_type(8))) unsigned short us8;

static __device__ __forceinline__ float b2f(unsigned short s) {
    unsigned u = ((unsigned)s) << 16;
    return __builtin_bit_cast(float, u);
}
static __device__ __forceinline__ unsigned short f2bf(float f) {
    unsigned u = __builtin_bit_cast(unsigned, f);
    u += 0x7fffu + ((u >> 16) & 1u);   // RNE
    return (unsigned short)(u >> 16);
}

// ---------------------------------------------------------------------------
// fp32 -> bf16 (RNE), 8 elements/thread, n must be divisible by 8*256.
// ---------------------------------------------------------------------------
__global__ __launch_bounds__(256) void cvt_bf16(const float* __restrict__ src,
                                                unsigned short* __restrict__ dst, int n8) {
    int i = blockIdx.x * 256 + threadIdx.x;
    if (i >= n8) return;
    const float4* s = (const float4*)src + (size_t)i * 2;
    float4 a = s[0], b = s[1];
    us8 o;
    o[0] = f2bf(a.x); o[1] = f2bf(a.y); o[2] = f2bf(a.z); o[3] = f2bf(a.w);
    o[4] = f2bf(b.x); o[5] = f2bf(b.y); o[6] = f2bf(b.z); o[7] = f2bf(b.w);
    *((us8*)dst + i) = o;
}

// ---------------------------------------------------------------------------
// MFMA GEMM (B-transposed): C[m,n] = sum_k A[m,k]*W[n,k], A,W bf16, K=1024.
// m97 structure: 128x128 tile, BK=64, 256 thr = 4 waves (2x2 of 64x64),
// global_load_lds width=16 staging, 16x16x32 bf16 MFMA, 4x4 tiles/wave.
// STORE_BF16: 1 -> C is bf16 (QKV path), 0 -> C is fp32 (final out).
// ---------------------------------------------------------------------------
template <int STORE_BF16>
__global__ __launch_bounds__(256) void mfma_gemm_bt(const unsigned short* __restrict__ A,
                                                    const unsigned short* __restrict__ W,
                                                    void* __restrict__ Cv, int N) {
    constexpr int K = 1024, BM = 128, BN = 128, BK = 64;
    __shared__ unsigned short As[BM * BK];   // row-major [m][k] — no padding (global_load_lds)
    __shared__ unsigned short Bs[BN * BK];   // row-major [n][k]

    const int tid  = threadIdx.x;
    const int w    = tid >> 6;
    const int lane = tid & 63;
    const int m0 = blockIdx.y * BM;
    const int n0 = blockIdx.x * BN;
    const int wr = (w >> 1) * 64;    // wave's m-offset in tile
    const int wc = (w & 1) * 64;     // wave's n-offset in tile

    const int srow   = lane >> 3;         // 0..7
    const int schunk = (lane & 7) * 8;    // k element offset, 8 bf16 = 16 B

    f32x4 acc[4][4] = {};

    for (int k0 = 0; k0 < K; k0 += BK) {
        __syncthreads();
#pragma unroll
        for (int t = 0; t < 4; ++t) {
            const int rbase = w * 32 + t * 8;   // 8 rows per wave-load
            const unsigned short* ga = A + (size_t)(m0 + rbase + srow) * K + k0 + schunk;
            __builtin_amdgcn_global_load_lds(
                (const __attribute__((address_space(1))) void*)ga,
                (__attribute__((address_space(3))) void*)(As + rbase * BK), 16, 0, 0);
            const unsigned short* gb = W + (size_t)(n0 + rbase + srow) * K + k0 + schunk;
            __builtin_amdgcn_global_load_lds(
                (const __attribute__((address_space(1))) void*)gb,
                (__attribute__((address_space(3))) void*)(Bs + rbase * BK), 16, 0, 0);
        }
        __syncthreads();   // compiler emits vmcnt(0) drain before barrier

        const int fr = lane & 15;
#pragma unroll
        for (int kk = 0; kk < BK; kk += 32) {
            const int fo = (lane >> 4) * 8 + kk;
            bf16x8 af[4], bfr[4];
#pragma unroll
            for (int i = 0; i < 4; ++i)
                af[i] = *(const bf16x8*)(As + (wr + i * 16 + fr) * BK + fo);
#pragma unroll
            for (int j = 0; j < 4; ++j)
                bfr[j] = *(const bf16x8*)(Bs + (wc + j * 16 + fr) * BK + fo);
#pragma unroll
            for (int i = 0; i < 4; ++i)
#pragma unroll
                for (int j = 0; j < 4; ++j)
                    acc[i][j] = __builtin_amdgcn_mfma_f32_16x16x32_bf16(af[i], bfr[j], acc[i][j], 0, 0, 0);
        }
    }

    // Epilogue. C/D layout: col = lane&15, row = (lane>>4)*4 + reg  [m89/m91].
    const int col = lane & 15;
    const int rq  = (lane >> 4) * 4;
#pragma unroll
    for (int i = 0; i < 4; ++i)
#pragma unroll
        for (int j = 0; j < 4; ++j)
#pragma unroll
            for (int r = 0; r < 4; ++r) {
                const int gm = m0 + wr + i * 16 + rq + r;
                const int gn = n0 + wc + j * 16 + col;
                if (STORE_BF16)
                    ((unsigned short*)Cv)[(size_t)gm * N + gn] = f2bf(acc[i][j][r]);
                else
                    ((float*)Cv)[(size_t)gm * N + gn] = acc[i][j][r];
            }
}

// ---------------------------------------------------------------------------
// Sliding-window ALiBi attention, fp32 math, bf16 in (qkv) / bf16 out (aout).
// qkvb: [M_ROWS, 3072] bf16; cols [0,1024)=Q, [1024,2048)=K, [2048,3072)=V.
// One block per (64-query tile, head, batch); 32-row K/V chunks, 10 chunks.
// ---------------------------------------------------------------------------
__global__ __launch_bounds__(256) void attn_win(const unsigned short* __restrict__ qkvb,
                                                const float* __restrict__ slopes,
                                                unsigned short* __restrict__ aoutb) {
    __shared__ float Qs[64][65];
    __shared__ float Ks[32][65];
    __shared__ float Vs[32][65];
    __shared__ float Ps[64][33];

    const int tid = threadIdx.x;
    const int tx = tid & 15;
    const int ty = tid >> 4;
    const int q0 = blockIdx.x * 64;
    const int h  = blockIdx.y;
    const int b  = blockIdx.z;
    const float slope = slopes[h];
    const size_t rowbase = (size_t)b * S_LEN * 3072;

    // Stage Q tile: 64 rows x 8 chunks of 8 bf16; 2 chunk-loads/thread.
#pragma unroll
    for (int e = 0; e < 2; ++e) {
        int idx = e * 256 + tid;          // 0..511
        int r = idx >> 3;                 // 0..63
        int c = (idx & 7) << 3;           // 0..56
        us8 v = *(const us8*)(qkvb + rowbase + (size_t)(q0 + r) * 3072 + h * DK + c);
#pragma unroll
        for (int t = 0; t < 8; ++t) Qs[r][c + t] = b2f(v[t]);
    }

    float m_i[4], l_i[4], o[4][4];
#pragma unroll
    for (int i = 0; i < 4; ++i) {
        m_i[i] = -1e30f; l_i[i] = 0.f;
#pragma unroll
        for (int j = 0; j < 4; ++j) o[i][j] = 0.f;
    }

    for (int c = 0; c < 10; ++c) {
        const int k0 = q0 - 128 + c * 32;
        __syncthreads();   // prev chunk reads done; fences Qs writes on c==0
        // Stage K/V chunk: 32 rows x 8 chunks each; 1 K-chunk + 1 V-chunk per thread.
        {
            int r  = tid >> 3;            // 0..31
            int cc = (tid & 7) << 3;      // 0..56
            int kpos = k0 + r;
            us8 kv = {0,0,0,0,0,0,0,0}, vv = {0,0,0,0,0,0,0,0};
            if (kpos >= 0 && kpos < S_LEN) {
                const unsigned short* kp = qkvb + rowbase + (size_t)kpos * 3072 + 1024 + h * DK + cc;
                kv = *(const us8*)kp;
                vv = *(const us8*)(kp + 1024);
            }
#pragma unroll
            for (int t = 0; t < 8; ++t) { Ks[r][cc + t] = b2f(kv[t]); Vs[r][cc + t] = b2f(vv[t]); }
        }
        __syncthreads();

        // Scores: 4 queries x 2 keys per thread.
        float s[4][2] = {{0.f}};
        for (int dd = 0; dd < 64; ++dd) {
            float qv[4], kv[2];
#pragma unroll
            for (int i = 0; i < 4; ++i) qv[i] = Qs[(ty << 2) + i][dd];
#pragma unroll
            for (int j = 0; j < 2; ++j) kv[j] = Ks[(tx << 1) + j][dd];
#pragma unroll
            for (int i = 0; i < 4; ++i)
#pragma unroll
                for (int j = 0; j < 2; ++j)
                    s[i][j] += qv[i] * kv[j];
        }

        // Bias + mask + online softmax update.
#pragma unroll
        for (int i = 0; i < 4; ++i) {
            const int qpos = q0 + (ty << 2) + i;
            float mx = -1e30f;
#pragma unroll
            for (int j = 0; j < 2; ++j) {
                const int kpos = k0 + (tx << 1) + j;
                const int rel = qpos - kpos;
                const bool ok = (kpos >= 0) && (kpos < S_LEN) && (rel <= 128) && (rel >= -128);
                s[i][j] = ok ? (s[i][j] * 0.125f + slope * (float)rel) : -1e30f;
                mx = fmaxf(mx, s[i][j]);
            }
#pragma unroll
            for (int off = 1; off < 16; off <<= 1) mx = fmaxf(mx, __shfl_xor(mx, off, 64));
            const float mnew = fmaxf(m_i[i], mx);
            const float alpha = __expf(m_i[i] - mnew);
            float psum = 0.f;
#pragma unroll
            for (int j = 0; j < 2; ++j) {
                float p = __expf(s[i][j] - mnew);
                if (s[i][j] < -9e29f) p = 0.f;
                s[i][j] = p;
                psum += p;
            }
#pragma unroll
            for (int off = 1; off < 16; off <<= 1) psum += __shfl_xor(psum, off, 64);
            l_i[i] = l_i[i] * alpha + psum;
            m_i[i] = mnew;
#pragma unroll
            for (int j = 0; j < 4; ++j) o[i][j] *= alpha;
#pragma unroll
            for (int j = 0; j < 2; ++j) Ps[(ty << 2) + i][(tx << 1) + j] = s[i][j];
        }
        __syncthreads();

        // PV accumulate.
        for (int kk = 0; kk < 32; ++kk) {
            float pv[4], vv[4];
#pragma unroll
            for (int i = 0; i < 4; ++i) pv[i] = Ps[(ty << 2) + i][kk];
#pragma unroll
            for (int j = 0; j < 4; ++j) vv[j] = Vs[kk][(tx << 2) + j];
#pragma unroll
            for (int i = 0; i < 4; ++i)
#pragma unroll
                for (int j = 0; j < 4; ++j)
                    o[i][j] += pv[i] * vv[j];
        }
    }

    // Epilogue: divide by l, write bf16 [B,S,D], col h*64 + 4*tx + j.
#pragma unroll
    for (int i = 0; i < 4; ++i) {
        const int qpos = q0 + (ty << 2) + i;
        const float inv = 1.f / l_i[i];
        ushort4 o4;
        o4.x = f2bf(o[i][0] * inv); o4.y = f2bf(o[i][1] * inv);
        o4.z = f2bf(o[i][2] * inv); o4.w = f2bf(o[i][3] * inv);
        *(ushort4*)(aoutb + ((size_t)b * S_LEN + qpos) * D_MODEL + h * DK + (tx << 2)) = o4;
    }
}

// ---------------------------------------------------------------------------
extern "C" void kernel_launch(void* const* d_in, const int* in_sizes, int n_in,
                              void* d_out, int out_size, void* d_ws, size_t ws_size,
                              hipStream_t stream) {
    const float* x      = (const float*)d_in[0];
    const float* Wq     = (const float*)d_in[1];
    const float* Wk     = (const float*)d_in[2];
    const float* Wv     = (const float*)d_in[3];
    const float* Wo     = (const float*)d_in[4];
    const float* slopes = (const float*)d_in[5];
    float* out = (float*)d_out;

    // Workspace layout (bf16 shorts), total 50.3 MB:
    unsigned short* xb    = (unsigned short*)d_ws;            // [4096,1024]
    unsigned short* wb    = xb    + (size_t)M_ROWS * D_MODEL; // [3072,1024] Wq|Wk|Wv
    unsigned short* wob   = wb    + (size_t)3072 * D_MODEL;   // [1024,1024]
    unsigned short* qkvb  = wob   + (size_t)1024 * D_MODEL;   // [4096,3072]
    unsigned short* aoutb = qkvb  + (size_t)M_ROWS * 3072;    // [4096,1024]

    dim3 blk(256);
    // 0) fp32 -> bf16 conversions
    cvt_bf16<<<2048, blk, 0, stream>>>(x,  xb,                 M_ROWS * D_MODEL / 8);
    cvt_bf16<<<512,  blk, 0, stream>>>(Wq, wb,                 D_MODEL * D_MODEL / 8);
    cvt_bf16<<<512,  blk, 0, stream>>>(Wk, wb + 1024 * 1024,   D_MODEL * D_MODEL / 8);
    cvt_bf16<<<512,  blk, 0, stream>>>(Wv, wb + 2 * 1024 * 1024, D_MODEL * D_MODEL / 8);
    cvt_bf16<<<512,  blk, 0, stream>>>(Wo, wob,                D_MODEL * D_MODEL / 8);
    // 1) fused QKV projection (bf16 MFMA, bf16 out)
    mfma_gemm_bt<1><<<dim3(3072 / 128, M_ROWS / 128), blk, 0, stream>>>(xb, wb, qkvb, 3072);
    // 2) windowed ALiBi attention (fp32 math, bf16 in/out)
    attn_win<<<dim3(S_LEN / 64, NH, BATCH), blk, 0, stream>>>(qkvb, slopes, aoutb);
    // 3) output projection (bf16 MFMA, fp32 out)
    mfma_gemm_bt<0><<<dim3(1024 / 128, M_ROWS / 128), blk, 0, stream>>>(aoutb, wob, out, 1024);
}

// Round 4
// 195.586 us; speedup vs baseline: 3.9666x; 1.9477x over previous
//
#include <hip/hip_runtime.h>
#include <hip/hip_bf16.h>

#define S_LEN   2048
#define D_MODEL 1024
#define NH      16
#define DK      64
#define BATCH   2
#define M_ROWS  (BATCH * S_LEN)   // 4096
#define LDP     72                // padded LDS row (bf16 elems): 144 B, 16B-aligned, non-pow2

typedef __attribute__((ext_vector_type(8))) short bf16x8;
typedef __attribute__((ext_vector_type(4))) float f32x4;
typedef __attribute__((ext_vector_type(8))) unsigned short us8;

static __device__ __forceinline__ float b2f(unsigned short s) {
    unsigned u = ((unsigned)s) << 16;
    return __builtin_bit_cast(float, u);
}
static __device__ __forceinline__ unsigned short f2bf(float f) {
    unsigned u = __builtin_bit_cast(unsigned, f);
    u += 0x7fffu + ((u >> 16) & 1u);   // RNE
    return (unsigned short)(u >> 16);
}

// ---------------------------------------------------------------------------
// fp32 -> bf16 (RNE), 8 elements/thread.
// ---------------------------------------------------------------------------
__global__ __launch_bounds__(256) void cvt_bf16(const float* __restrict__ src,
                                                unsigned short* __restrict__ dst, int n8) {
    int i = blockIdx.x * 256 + threadIdx.x;
    if (i >= n8) return;
    const float4* s = (const float4*)src + (size_t)i * 2;
    float4 a = s[0], b = s[1];
    us8 o;
    o[0] = f2bf(a.x); o[1] = f2bf(a.y); o[2] = f2bf(a.z); o[3] = f2bf(a.w);
    o[4] = f2bf(b.x); o[5] = f2bf(b.y); o[6] = f2bf(b.z); o[7] = f2bf(b.w);
    *((us8*)dst + i) = o;
}

// ---------------------------------------------------------------------------
// MFMA GEMM (B-transposed): C[m,n] = sum_k A[m,k]*W[n,k], A,W bf16, K=1024.
// m97 structure: 128x128 tile, BK=64, global_load_lds width=16.
// ---------------------------------------------------------------------------
template <int STORE_BF16>
__global__ __launch_bounds__(256) void mfma_gemm_bt(const unsigned short* __restrict__ A,
                                                    const unsigned short* __restrict__ W,
                                                    void* __restrict__ Cv, int N) {
    constexpr int K = 1024, BM = 128, BN = 128, BK = 64;
    __shared__ unsigned short As[BM * BK];
    __shared__ unsigned short Bs[BN * BK];

    const int tid  = threadIdx.x;
    const int w    = tid >> 6;
    const int lane = tid & 63;
    const int m0 = blockIdx.y * BM;
    const int n0 = blockIdx.x * BN;
    const int wr = (w >> 1) * 64;
    const int wc = (w & 1) * 64;

    const int srow   = lane >> 3;
    const int schunk = (lane & 7) * 8;

    f32x4 acc[4][4] = {};

    for (int k0 = 0; k0 < K; k0 += BK) {
        __syncthreads();
#pragma unroll
        for (int t = 0; t < 4; ++t) {
            const int rbase = w * 32 + t * 8;
            const unsigned short* ga = A + (size_t)(m0 + rbase + srow) * K + k0 + schunk;
            __builtin_amdgcn_global_load_lds(
                (const __attribute__((address_space(1))) void*)ga,
                (__attribute__((address_space(3))) void*)(As + rbase * BK), 16, 0, 0);
            const unsigned short* gb = W + (size_t)(n0 + rbase + srow) * K + k0 + schunk;
            __builtin_amdgcn_global_load_lds(
                (const __attribute__((address_space(1))) void*)gb,
                (__attribute__((address_space(3))) void*)(Bs + rbase * BK), 16, 0, 0);
        }
        __syncthreads();

        const int fr = lane & 15;
#pragma unroll
        for (int kk = 0; kk < BK; kk += 32) {
            const int fo = (lane >> 4) * 8 + kk;
            bf16x8 af[4], bfr[4];
#pragma unroll
            for (int i = 0; i < 4; ++i)
                af[i] = *(const bf16x8*)(As + (wr + i * 16 + fr) * BK + fo);
#pragma unroll
            for (int j = 0; j < 4; ++j)
                bfr[j] = *(const bf16x8*)(Bs + (wc + j * 16 + fr) * BK + fo);
#pragma unroll
            for (int i = 0; i < 4; ++i)
#pragma unroll
                for (int j = 0; j < 4; ++j)
                    acc[i][j] = __builtin_amdgcn_mfma_f32_16x16x32_bf16(af[i], bfr[j], acc[i][j], 0, 0, 0);
        }
    }

    const int col = lane & 15;
    const int rq  = (lane >> 4) * 4;
#pragma unroll
    for (int i = 0; i < 4; ++i)
#pragma unroll
        for (int j = 0; j < 4; ++j)
#pragma unroll
            for (int r = 0; r < 4; ++r) {
                const int gm = m0 + wr + i * 16 + rq + r;
                const int gn = n0 + wc + j * 16 + col;
                if (STORE_BF16)
                    ((unsigned short*)Cv)[(size_t)gm * N + gn] = f2bf(acc[i][j][r]);
                else
                    ((float*)Cv)[(size_t)gm * N + gn] = acc[i][j][r];
            }
}

// ---------------------------------------------------------------------------
// MFMA sliding-window ALiBi attention.
// qkvb: [M_ROWS, 3072] bf16; Q|K|V each [*,1024], head h at col h*64.
// Block: 256 thr = 4 waves; 64-query tile, head, batch. 5 chunks of 64 keys
// spanning [q0-128, q0+192). Wave w owns q rows [w*16, w*16+16).
//   QK^T: A-frag from Qs rows, B-frag from Ks rows (native [key][d]).
//   Softmax fp32 on C-layout frag (row = (lane>>4)*4+reg, col = lane&15).
//   P -> LDS bf16 (C-layout -> A-layout transform), V staged transposed
//   (Vt[d][key]) so PV B-frags are vector reads.
// All LDS rows padded to LDP=72 bf16 (144 B) to break pow2 bank strides.
// ---------------------------------------------------------------------------
__global__ __launch_bounds__(256) void attn_mfma(const unsigned short* __restrict__ qkvb,
                                                 const float* __restrict__ slopes,
                                                 unsigned short* __restrict__ aoutb) {
    __shared__ unsigned short Qs[64 * LDP];
    __shared__ unsigned short Ks[64 * LDP];
    __shared__ unsigned short Vt[64 * LDP];   // [d][key]
    __shared__ unsigned short Ps[64 * LDP];   // per-wave private 16-row strips

    const int tid  = threadIdx.x;
    const int w    = tid >> 6;
    const int lane = tid & 63;
    const int q0 = blockIdx.x * 64;
    const int h  = blockIdx.y;
    const int b  = blockIdx.z;
    const float slope = slopes[h];
    const size_t rowbase = (size_t)b * S_LEN * 3072;

    // Stage Q tile: 64 rows x 8 us8 chunks = 512; 2 per thread.
#pragma unroll
    for (int e = 0; e < 2; ++e) {
        int idx = e * 256 + tid;
        int r = idx >> 3, cc = (idx & 7) * 8;
        us8 v = *(const us8*)(qkvb + rowbase + (size_t)(q0 + r) * 3072 + h * DK + cc);
        *(us8*)(Qs + r * LDP + cc) = v;
    }

    const int col = lane & 15;
    const int rq  = (lane >> 4) * 4;
    const int wq  = w * 16;                 // wave's q-offset in tile
    const int fo  = (lane >> 4) * 8;        // fragment k-offset

    f32x4 o_acc[4] = {};                    // j = d-tile, 4 regs = 4 q-rows
    float m_i[4], l_i[4];
#pragma unroll
    for (int r = 0; r < 4; ++r) { m_i[r] = -1e30f; l_i[r] = 0.f; }

    for (int c = 0; c < 5; ++c) {
        const int k0 = q0 - 128 + c * 64;
        __syncthreads();   // prev chunk's Ks/Vt reads done; fences Qs on c==0

        // Stage K chunk: 64 rows x 8 us8 = 512; 2 per thread.
#pragma unroll
        for (int e = 0; e < 2; ++e) {
            int idx = e * 256 + tid;
            int r = idx >> 3, cc = (idx & 7) * 8;
            int kpos = k0 + r;
            us8 kv = {0, 0, 0, 0, 0, 0, 0, 0};
            if ((unsigned)kpos < (unsigned)S_LEN)
                kv = *(const us8*)(qkvb + rowbase + (size_t)kpos * 3072 + 1024 + h * DK + cc);
            *(us8*)(Ks + r * LDP + cc) = kv;
        }
        // Stage V transposed: thread owns key-pair (2 rows) x 8 d values.
        {
            int rp = tid >> 3;              // key pair index 0..31
            int cc = (tid & 7) * 8;         // d chunk
            int kp0 = k0 + rp * 2;
            us8 v0 = {0, 0, 0, 0, 0, 0, 0, 0}, v1 = {0, 0, 0, 0, 0, 0, 0, 0};
            if ((unsigned)kp0 < (unsigned)S_LEN)
                v0 = *(const us8*)(qkvb + rowbase + (size_t)kp0 * 3072 + 2048 + h * DK + cc);
            if ((unsigned)(kp0 + 1) < (unsigned)S_LEN)
                v1 = *(const us8*)(qkvb + rowbase + (size_t)(kp0 + 1) * 3072 + 2048 + h * DK + cc);
#pragma unroll
            for (int t = 0; t < 8; ++t) {
                unsigned pk = (unsigned)(unsigned short)v0[t] | ((unsigned)(unsigned short)v1[t] << 16);
                *(unsigned*)(Vt + (cc + t) * LDP + rp * 2) = pk;
            }
        }
        __syncthreads();

        // --- QK^T: 8 MFMAs -> S[q=wq+rq+r][key=j*16+col] ---
        f32x4 sacc[4] = {};
        {
            bf16x8 aq0 = *(const bf16x8*)(Qs + (wq + col) * LDP + fo);
            bf16x8 aq1 = *(const bf16x8*)(Qs + (wq + col) * LDP + fo + 32);
#pragma unroll
            for (int j = 0; j < 4; ++j) {
                bf16x8 bk0 = *(const bf16x8*)(Ks + (j * 16 + col) * LDP + fo);
                bf16x8 bk1 = *(const bf16x8*)(Ks + (j * 16 + col) * LDP + fo + 32);
                sacc[j] = __builtin_amdgcn_mfma_f32_16x16x32_bf16(aq0, bk0, sacc[j], 0, 0, 0);
                sacc[j] = __builtin_amdgcn_mfma_f32_16x16x32_bf16(aq1, bk1, sacc[j], 0, 0, 0);
            }
        }

        // --- scale + ALiBi + mask ---
        float sv[4][4];   // [j][r]
#pragma unroll
        for (int j = 0; j < 4; ++j) {
            const int kpos = k0 + j * 16 + col;
            const bool kin = (unsigned)kpos < (unsigned)S_LEN;
#pragma unroll
            for (int r = 0; r < 4; ++r) {
                const int rel = (q0 + wq + rq + r) - kpos;
                const bool ok = kin && (rel <= 128) && (rel >= -128);
                sv[j][r] = ok ? (sacc[j][r] * 0.125f + slope * (float)rel) : -1e30f;
            }
        }

        // --- online softmax (per q-row r; 16-lane group reductions) ---
#pragma unroll
        for (int r = 0; r < 4; ++r) {
            float mx = fmaxf(fmaxf(sv[0][r], sv[1][r]), fmaxf(sv[2][r], sv[3][r]));
#pragma unroll
            for (int off = 1; off < 16; off <<= 1) mx = fmaxf(mx, __shfl_xor(mx, off, 64));
            const float mnew = fmaxf(m_i[r], mx);
            const float alpha = __expf(m_i[r] - mnew);
            float ps = 0.f;
#pragma unroll
            for (int j = 0; j < 4; ++j) {
                float p = (sv[j][r] < -9e29f) ? 0.f : __expf(sv[j][r] - mnew);
                sv[j][r] = p;
                ps += p;
            }
#pragma unroll
            for (int off = 1; off < 16; off <<= 1) ps += __shfl_xor(ps, off, 64);
            l_i[r] = l_i[r] * alpha + ps;
            m_i[r] = mnew;
#pragma unroll
            for (int j = 0; j < 4; ++j) o_acc[j][r] *= alpha;
        }

        // --- P to LDS (C-layout -> memory [q][key]) ---
#pragma unroll
        for (int j = 0; j < 4; ++j)
#pragma unroll
            for (int r = 0; r < 4; ++r)
                Ps[(wq + rq + r) * LDP + j * 16 + col] = f2bf(sv[j][r]);
        __syncthreads();   // safety: order P writes before A-frag reads

        // --- PV: 8 MFMAs -> O[q][d=j*16+col] ---
        {
            bf16x8 ap0 = *(const bf16x8*)(Ps + (wq + col) * LDP + fo);
            bf16x8 ap1 = *(const bf16x8*)(Ps + (wq + col) * LDP + fo + 32);
#pragma unroll
            for (int j = 0; j < 4; ++j) {
                bf16x8 bv0 = *(const bf16x8*)(Vt + (j * 16 + col) * LDP + fo);
                bf16x8 bv1 = *(const bf16x8*)(Vt + (j * 16 + col) * LDP + fo + 32);
                o_acc[j] = __builtin_amdgcn_mfma_f32_16x16x32_bf16(ap0, bv0, o_acc[j], 0, 0, 0);
                o_acc[j] = __builtin_amdgcn_mfma_f32_16x16x32_bf16(ap1, bv1, o_acc[j], 0, 0, 0);
            }
        }
    }

    // Epilogue: O / l_i, bf16 store to [B,S,D] col h*64 + j*16 + col.
    float inv[4];
#pragma unroll
    for (int r = 0; r < 4; ++r) inv[r] = 1.f / l_i[r];
#pragma unroll
    for (int j = 0; j < 4; ++j)
#pragma unroll
        for (int r = 0; r < 4; ++r) {
            const int qpos = q0 + wq + rq + r;
            aoutb[((size_t)b * S_LEN + qpos) * D_MODEL + h * DK + j * 16 + col] =
                f2bf(o_acc[j][r] * inv[r]);
        }
}

// ---------------------------------------------------------------------------
extern "C" void kernel_launch(void* const* d_in, const int* in_sizes, int n_in,
                              void* d_out, int out_size, void* d_ws, size_t ws_size,
                              hipStream_t stream) {
    const float* x      = (const float*)d_in[0];
    const float* Wq     = (const float*)d_in[1];
    const float* Wk     = (const float*)d_in[2];
    const float* Wv     = (const float*)d_in[3];
    const float* Wo     = (const float*)d_in[4];
    const float* slopes = (const float*)d_in[5];
    float* out = (float*)d_out;

    unsigned short* xb    = (unsigned short*)d_ws;            // [4096,1024]
    unsigned short* wb    = xb    + (size_t)M_ROWS * D_MODEL; // [3072,1024] Wq|Wk|Wv
    unsigned short* wob   = wb    + (size_t)3072 * D_MODEL;   // [1024,1024]
    unsigned short* qkvb  = wob   + (size_t)1024 * D_MODEL;   // [4096,3072]
    unsigned short* aoutb = qkvb  + (size_t)M_ROWS * 3072;    // [4096,1024]

    dim3 blk(256);
    cvt_bf16<<<2048, blk, 0, stream>>>(x,  xb,                   M_ROWS * D_MODEL / 8);
    cvt_bf16<<<512,  blk, 0, stream>>>(Wq, wb,                   D_MODEL * D_MODEL / 8);
    cvt_bf16<<<512,  blk, 0, stream>>>(Wk, wb + 1024 * 1024,     D_MODEL * D_MODEL / 8);
    cvt_bf16<<<512,  blk, 0, stream>>>(Wv, wb + 2 * 1024 * 1024, D_MODEL * D_MODEL / 8);
    cvt_bf16<<<512,  blk, 0, stream>>>(Wo, wob,                  D_MODEL * D_MODEL / 8);
    mfma_gemm_bt<1><<<dim3(3072 / 128, M_ROWS / 128), blk, 0, stream>>>(xb, wb, qkvb, 3072);
    attn_mfma<<<dim3(S_LEN / 64, NH, BATCH), blk, 0, stream>>>(qkvb, slopes, aoutb);
    mfma_gemm_bt<0><<<dim3(1024 / 128, M_ROWS / 128), blk, 0, stream>>>(aoutb, wob, out, 1024);
}

// Round 5
// 173.722 us; speedup vs baseline: 4.4658x; 1.1259x over previous
//
#include <hip/hip_runtime.h>
#include <hip/hip_bf16.h>

#define S_LEN   2048
#define D_MODEL 1024
#define NH      16
#define DK      64
#define BATCH   2
#define M_ROWS  (BATCH * S_LEN)   // 4096
#define LDP     72                // padded LDS row (bf16 elems) for attn kernel

typedef __attribute__((ext_vector_type(8))) short bf16x8;
typedef __attribute__((ext_vector_type(4))) float f32x4;
typedef __attribute__((ext_vector_type(8))) unsigned short us8;

static __device__ __forceinline__ float b2f(unsigned short s) {
    unsigned u = ((unsigned)s) << 16;
    return __builtin_bit_cast(float, u);
}
static __device__ __forceinline__ unsigned short f2bf(float f) {
    unsigned u = __builtin_bit_cast(unsigned, f);
    u += 0x7fffu + ((u >> 16) & 1u);   // RNE
    return (unsigned short)(u >> 16);
}

// ---------------------------------------------------------------------------
// fp32 -> bf16 (RNE), 8 elements/thread.
// ---------------------------------------------------------------------------
__global__ __launch_bounds__(256) void cvt_bf16(const float* __restrict__ src,
                                                unsigned short* __restrict__ dst, int n8) {
    int i = blockIdx.x * 256 + threadIdx.x;
    if (i >= n8) return;
    const float4* s = (const float4*)src + (size_t)i * 2;
    float4 a = s[0], b = s[1];
    us8 o;
    o[0] = f2bf(a.x); o[1] = f2bf(a.y); o[2] = f2bf(a.z); o[3] = f2bf(a.w);
    o[4] = f2bf(b.x); o[5] = f2bf(b.y); o[6] = f2bf(b.z); o[7] = f2bf(b.w);
    *((us8*)dst + i) = o;
}

// All four 1024x1024 weight matrices in one launch; dst strips are contiguous
// (wb: Wq|Wk|Wv then wob immediately after). 512 blocks per matrix.
__global__ __launch_bounds__(256) void cvt_bf16_w4(const float* __restrict__ s0,
                                                   const float* __restrict__ s1,
                                                   const float* __restrict__ s2,
                                                   const float* __restrict__ s3,
                                                   unsigned short* __restrict__ dst) {
    const int which = blockIdx.x >> 9;
    const float* src = (which == 0) ? s0 : (which == 1) ? s1 : (which == 2) ? s2 : s3;
    const int i = (blockIdx.x & 511) * 256 + threadIdx.x;       // 0..131071
    const float4* s = (const float4*)src + (size_t)i * 2;
    float4 a = s[0], b = s[1];
    us8 o;
    o[0] = f2bf(a.x); o[1] = f2bf(a.y); o[2] = f2bf(a.z); o[3] = f2bf(a.w);
    o[4] = f2bf(b.x); o[5] = f2bf(b.y); o[6] = f2bf(b.z); o[7] = f2bf(b.w);
    *((us8*)(dst + (size_t)which * 1024 * 1024) + i) = o;
}

// ---------------------------------------------------------------------------
// MFMA GEMM (B-transposed): C[m,n] = sum_k A[m,k]*W[n,k], A,W bf16, K=1024.
// m97 structure: 128x128 tile, BK=64, global_load_lds width=16.
// XOR-swizzled LDS (16B-chunk granularity): LDS (row, p) holds global chunk
// p ^ (row&7). global_load_lds pins LDS dst = lane*16, so the swizzle is
// realized by permuting per-lane GLOBAL addresses. Fragment rows all have
// row&7 == lane&7, so read-side swizzle is two per-lane constants.
// Kills the 128B-stride bank conflicts (9.4e6/dispatch -> ~free).
// ---------------------------------------------------------------------------
template <int STORE_BF16>
__global__ __launch_bounds__(256) void mfma_gemm_bt(const unsigned short* __restrict__ A,
                                                    const unsigned short* __restrict__ W,
                                                    void* __restrict__ Cv, int N) {
    constexpr int K = 1024, BM = 128, BN = 128, BK = 64;
    __shared__ unsigned short As[BM * BK];
    __shared__ unsigned short Bs[BN * BK];

    const int tid  = threadIdx.x;
    const int w    = tid >> 6;
    const int lane = tid & 63;
    const int m0 = blockIdx.y * BM;
    const int n0 = blockIdx.x * BN;
    const int wr = (w >> 1) * 64;
    const int wc = (w & 1) * 64;

    const int srow   = lane >> 3;                          // 0..7
    const int schunk = ((lane & 7) ^ (lane >> 3)) * 8;     // swizzled k-chunk (elems)

    // Read-side swizzled chunk offsets (elems): data chunk g read from LDS
    // position g ^ (row&7); row&7 == lane&7 for every fragment row.
    const int sw = lane & 7;
    const int c0 = (((lane >> 4) + 0) ^ sw) * 8;           // kk = 0
    const int c1 = (((lane >> 4) + 4) ^ sw) * 8;           // kk = 32

    f32x4 acc[4][4] = {};

    for (int k0 = 0; k0 < K; k0 += BK) {
        __syncthreads();
#pragma unroll
        for (int t = 0; t < 4; ++t) {
            const int rbase = w * 32 + t * 8;              // multiple of 8
            const unsigned short* ga = A + (size_t)(m0 + rbase + srow) * K + k0 + schunk;
            __builtin_amdgcn_global_load_lds(
                (const __attribute__((address_space(1))) void*)ga,
                (__attribute__((address_space(3))) void*)(As + rbase * BK), 16, 0, 0);
            const unsigned short* gb = W + (size_t)(n0 + rbase + srow) * K + k0 + schunk;
            __builtin_amdgcn_global_load_lds(
                (const __attribute__((address_space(1))) void*)gb,
                (__attribute__((address_space(3))) void*)(Bs + rbase * BK), 16, 0, 0);
        }
        __syncthreads();

        const int fr = lane & 15;
#pragma unroll
        for (int kk = 0; kk < 2; ++kk) {
            const int co = kk ? c1 : c0;
            bf16x8 af[4], bfr[4];
#pragma unroll
            for (int i = 0; i < 4; ++i)
                af[i] = *(const bf16x8*)(As + (wr + i * 16 + fr) * BK + co);
#pragma unroll
            for (int j = 0; j < 4; ++j)
                bfr[j] = *(const bf16x8*)(Bs + (wc + j * 16 + fr) * BK + co);
#pragma unroll
            for (int i = 0; i < 4; ++i)
#pragma unroll
                for (int j = 0; j < 4; ++j)
                    acc[i][j] = __builtin_amdgcn_mfma_f32_16x16x32_bf16(af[i], bfr[j], acc[i][j], 0, 0, 0);
        }
    }

    const int col = lane & 15;
    const int rq  = (lane >> 4) * 4;
#pragma unroll
    for (int i = 0; i < 4; ++i)
#pragma unroll
        for (int j = 0; j < 4; ++j)
#pragma unroll
            for (int r = 0; r < 4; ++r) {
                const int gm = m0 + wr + i * 16 + rq + r;
                const int gn = n0 + wc + j * 16 + col;
                if (STORE_BF16)
                    ((unsigned short*)Cv)[(size_t)gm * N + gn] = f2bf(acc[i][j][r]);
                else
                    ((float*)Cv)[(size_t)gm * N + gn] = acc[i][j][r];
            }
}

// ---------------------------------------------------------------------------
// MFMA sliding-window ALiBi attention (unchanged from round 3).
// ---------------------------------------------------------------------------
__global__ __launch_bounds__(256) void attn_mfma(const unsigned short* __restrict__ qkvb,
                                                 const float* __restrict__ slopes,
                                                 unsigned short* __restrict__ aoutb) {
    __shared__ unsigned short Qs[64 * LDP];
    __shared__ unsigned short Ks[64 * LDP];
    __shared__ unsigned short Vt[64 * LDP];   // [d][key]
    __shared__ unsigned short Ps[64 * LDP];

    const int tid  = threadIdx.x;
    const int w    = tid >> 6;
    const int lane = tid & 63;
    const int q0 = blockIdx.x * 64;
    const int h  = blockIdx.y;
    const int b  = blockIdx.z;
    const float slope = slopes[h];
    const size_t rowbase = (size_t)b * S_LEN * 3072;

#pragma unroll
    for (int e = 0; e < 2; ++e) {
        int idx = e * 256 + tid;
        int r = idx >> 3, cc = (idx & 7) * 8;
        us8 v = *(const us8*)(qkvb + rowbase + (size_t)(q0 + r) * 3072 + h * DK + cc);
        *(us8*)(Qs + r * LDP + cc) = v;
    }

    const int col = lane & 15;
    const int rq  = (lane >> 4) * 4;
    const int wq  = w * 16;
    const int fo  = (lane >> 4) * 8;

    f32x4 o_acc[4] = {};
    float m_i[4], l_i[4];
#pragma unroll
    for (int r = 0; r < 4; ++r) { m_i[r] = -1e30f; l_i[r] = 0.f; }

    for (int c = 0; c < 5; ++c) {
        const int k0 = q0 - 128 + c * 64;
        __syncthreads();

#pragma unroll
        for (int e = 0; e < 2; ++e) {
            int idx = e * 256 + tid;
            int r = idx >> 3, cc = (idx & 7) * 8;
            int kpos = k0 + r;
            us8 kv = {0, 0, 0, 0, 0, 0, 0, 0};
            if ((unsigned)kpos < (unsigned)S_LEN)
                kv = *(const us8*)(qkvb + rowbase + (size_t)kpos * 3072 + 1024 + h * DK + cc);
            *(us8*)(Ks + r * LDP + cc) = kv;
        }
        {
            int rp = tid >> 3;
            int cc = (tid & 7) * 8;
            int kp0 = k0 + rp * 2;
            us8 v0 = {0, 0, 0, 0, 0, 0, 0, 0}, v1 = {0, 0, 0, 0, 0, 0, 0, 0};
            if ((unsigned)kp0 < (unsigned)S_LEN)
                v0 = *(const us8*)(qkvb + rowbase + (size_t)kp0 * 3072 + 2048 + h * DK + cc);
            if ((unsigned)(kp0 + 1) < (unsigned)S_LEN)
                v1 = *(const us8*)(qkvb + rowbase + (size_t)(kp0 + 1) * 3072 + 2048 + h * DK + cc);
#pragma unroll
            for (int t = 0; t < 8; ++t) {
                unsigned pk = (unsigned)(unsigned short)v0[t] | ((unsigned)(unsigned short)v1[t] << 16);
                *(unsigned*)(Vt + (cc + t) * LDP + rp * 2) = pk;
            }
        }
        __syncthreads();

        f32x4 sacc[4] = {};
        {
            bf16x8 aq0 = *(const bf16x8*)(Qs + (wq + col) * LDP + fo);
            bf16x8 aq1 = *(const bf16x8*)(Qs + (wq + col) * LDP + fo + 32);
#pragma unroll
            for (int j = 0; j < 4; ++j) {
                bf16x8 bk0 = *(const bf16x8*)(Ks + (j * 16 + col) * LDP + fo);
                bf16x8 bk1 = *(const bf16x8*)(Ks + (j * 16 + col) * LDP + fo + 32);
                sacc[j] = __builtin_amdgcn_mfma_f32_16x16x32_bf16(aq0, bk0, sacc[j], 0, 0, 0);
                sacc[j] = __builtin_amdgcn_mfma_f32_16x16x32_bf16(aq1, bk1, sacc[j], 0, 0, 0);
            }
        }

        float sv[4][4];
#pragma unroll
        for (int j = 0; j < 4; ++j) {
            const int kpos = k0 + j * 16 + col;
            const bool kin = (unsigned)kpos < (unsigned)S_LEN;
#pragma unroll
            for (int r = 0; r < 4; ++r) {
                const int rel = (q0 + wq + rq + r) - kpos;
                const bool ok = kin && (rel <= 128) && (rel >= -128);
                sv[j][r] = ok ? (sacc[j][r] * 0.125f + slope * (float)rel) : -1e30f;
            }
        }

#pragma unroll
        for (int r = 0; r < 4; ++r) {
            float mx = fmaxf(fmaxf(sv[0][r], sv[1][r]), fmaxf(sv[2][r], sv[3][r]));
#pragma unroll
            for (int off = 1; off < 16; off <<= 1) mx = fmaxf(mx, __shfl_xor(mx, off, 64));
            const float mnew = fmaxf(m_i[r], mx);
            const float alpha = __expf(m_i[r] - mnew);
            float ps = 0.f;
#pragma unroll
            for (int j = 0; j < 4; ++j) {
                float p = (sv[j][r] < -9e29f) ? 0.f : __expf(sv[j][r] - mnew);
                sv[j][r] = p;
                ps += p;
            }
#pragma unroll
            for (int off = 1; off < 16; off <<= 1) ps += __shfl_xor(ps, off, 64);
            l_i[r] = l_i[r] * alpha + ps;
            m_i[r] = mnew;
#pragma unroll
            for (int j = 0; j < 4; ++j) o_acc[j][r] *= alpha;
        }

#pragma unroll
        for (int j = 0; j < 4; ++j)
#pragma unroll
            for (int r = 0; r < 4; ++r)
                Ps[(wq + rq + r) * LDP + j * 16 + col] = f2bf(sv[j][r]);
        __syncthreads();

        {
            bf16x8 ap0 = *(const bf16x8*)(Ps + (wq + col) * LDP + fo);
            bf16x8 ap1 = *(const bf16x8*)(Ps + (wq + col) * LDP + fo + 32);
#pragma unroll
            for (int j = 0; j < 4; ++j) {
                bf16x8 bv0 = *(const bf16x8*)(Vt + (j * 16 + col) * LDP + fo);
                bf16x8 bv1 = *(const bf16x8*)(Vt + (j * 16 + col) * LDP + fo + 32);
                o_acc[j] = __builtin_amdgcn_mfma_f32_16x16x32_bf16(ap0, bv0, o_acc[j], 0, 0, 0);
                o_acc[j] = __builtin_amdgcn_mfma_f32_16x16x32_bf16(ap1, bv1, o_acc[j], 0, 0, 0);
            }
        }
    }

    float inv[4];
#pragma unroll
    for (int r = 0; r < 4; ++r) inv[r] = 1.f / l_i[r];
#pragma unroll
    for (int j = 0; j < 4; ++j)
#pragma unroll
        for (int r = 0; r < 4; ++r) {
            const int qpos = q0 + wq + rq + r;
            aoutb[((size_t)b * S_LEN + qpos) * D_MODEL + h * DK + j * 16 + col] =
                f2bf(o_acc[j][r] * inv[r]);
        }
}

// ---------------------------------------------------------------------------
extern "C" void kernel_launch(void* const* d_in, const int* in_sizes, int n_in,
                              void* d_out, int out_size, void* d_ws, size_t ws_size,
                              hipStream_t stream) {
    const float* x      = (const float*)d_in[0];
    const float* Wq     = (const float*)d_in[1];
    const float* Wk     = (const float*)d_in[2];
    const float* Wv     = (const float*)d_in[3];
    const float* Wo     = (const float*)d_in[4];
    const float* slopes = (const float*)d_in[5];
    float* out = (float*)d_out;

    unsigned short* xb    = (unsigned short*)d_ws;            // [4096,1024]
    unsigned short* wb    = xb    + (size_t)M_ROWS * D_MODEL; // [3072,1024] Wq|Wk|Wv
    unsigned short* wob   = wb    + (size_t)3072 * D_MODEL;   // [1024,1024] (contiguous after wb)
    unsigned short* qkvb  = wob   + (size_t)1024 * D_MODEL;   // [4096,3072]
    unsigned short* aoutb = qkvb  + (size_t)M_ROWS * 3072;    // [4096,1024]

    dim3 blk(256);
    cvt_bf16<<<2048, blk, 0, stream>>>(x, xb, M_ROWS * D_MODEL / 8);
    cvt_bf16_w4<<<2048, blk, 0, stream>>>(Wq, Wk, Wv, Wo, wb);
    mfma_gemm_bt<1><<<dim3(3072 / 128, M_ROWS / 128), blk, 0, stream>>>(xb, wb, qkvb, 3072);
    attn_mfma<<<dim3(S_LEN / 64, NH, BATCH), blk, 0, stream>>>(qkvb, slopes, aoutb);
    mfma_gemm_bt<0><<<dim3(1024 / 128, M_ROWS / 128), blk, 0, stream>>>(aoutb, wob, out, 1024);
}

// Round 7
// 159.625 us; speedup vs baseline: 4.8602x; 1.0883x over previous
//
#include <hip/hip_runtime.h>
#include <hip/hip_bf16.h>

#define S_LEN   2048
#define D_MODEL 1024
#define NH      16
#define DK      64
#define BATCH   2
#define M_ROWS  (BATCH * S_LEN)   // 4096
#define LDP     72                // padded LDS row (bf16 elems) for attn kernel
#define LDW     132               // epilogue LDS stride (elems): 264B -> conflict-free

typedef __attribute__((ext_vector_type(8))) short bf16x8;
typedef __attribute__((ext_vector_type(4))) float f32x4;
typedef __attribute__((ext_vector_type(8))) unsigned short us8;
typedef __attribute__((ext_vector_type(4))) unsigned short us4;

static __device__ __forceinline__ float b2f(unsigned short s) {
    unsigned u = ((unsigned)s) << 16;
    return __builtin_bit_cast(float, u);
}
static __device__ __forceinline__ unsigned short f2bf(float f) {
    unsigned u = __builtin_bit_cast(unsigned, f);
    u += 0x7fffu + ((u >> 16) & 1u);   // RNE
    return (unsigned short)(u >> 16);
}

// ---------------------------------------------------------------------------
// All fp32->bf16 conversions in ONE launch. dst = xb; weight strips follow
// contiguously (xb | Wq | Wk | Wv | Wo as bf16).
// ---------------------------------------------------------------------------
__global__ __launch_bounds__(256) void cvt_all(const float* __restrict__ x,
                                               const float* __restrict__ wq,
                                               const float* __restrict__ wk,
                                               const float* __restrict__ wv,
                                               const float* __restrict__ wo,
                                               unsigned short* __restrict__ dst) {
    const int b = blockIdx.x;
    if (b < 2048) {
        const size_t o8 = (size_t)b * 256 + threadIdx.x;
        const float4* s = (const float4*)x + o8 * 2;
        float4 a = s[0], bb = s[1];
        us8 o;
        o[0] = f2bf(a.x);  o[1] = f2bf(a.y);  o[2] = f2bf(a.z);  o[3] = f2bf(a.w);
        o[4] = f2bf(bb.x); o[5] = f2bf(bb.y); o[6] = f2bf(bb.z); o[7] = f2bf(bb.w);
        *((us8*)dst + o8) = o;
    } else {
        const int wi = (b - 2048) >> 9;
        const float* src = (wi == 0) ? wq : (wi == 1) ? wk : (wi == 2) ? wv : wo;
        const size_t local = (size_t)((b - 2048) & 511) * 256 + threadIdx.x;
        const float4* s = (const float4*)src + local * 2;
        float4 a = s[0], bb = s[1];
        us8 o;
        o[0] = f2bf(a.x);  o[1] = f2bf(a.y);  o[2] = f2bf(a.z);  o[3] = f2bf(a.w);
        o[4] = f2bf(bb.x); o[5] = f2bf(bb.y); o[6] = f2bf(bb.z); o[7] = f2bf(bb.w);
        *((us8*)dst + 524288 + (size_t)wi * 131072 + local) = o;
    }
}

// ---------------------------------------------------------------------------
// MFMA GEMM (B-transposed): C[m,n] = sum_k A[m,k]*W[n,k], bf16 in, K=1024.
// BM=128, BK=64, XOR-swizzled global_load_lds staging.
// BN=128: 4 waves 2x2, 4x4 frags/wave, LDS-vectorized bf16 epilogue.
// BN=64:  4 waves 4x1, 2x4 frags/wave (Wo grid: 512 blocks = 2/CU).
// ROUND-6 FIX: B staging wave stride is BN/4 (= (BN/32)*8), NOT BN/8 —
// round 5's BN/8 left the upper Bs rows unstaged -> NaN.
// ---------------------------------------------------------------------------
template <int STORE_BF16, int BN>
__global__ __launch_bounds__(256) void mfma_gemm_bt(const unsigned short* __restrict__ A,
                                                    const unsigned short* __restrict__ W,
                                                    void* __restrict__ Cv, int N) {
    constexpr int K = 1024, BM = 128, BK = 64;
    constexpr int MI = (BN == 128) ? 4 : 2;
    constexpr int SMEM = (STORE_BF16 && BN == 128) ? (128 * LDW)
                                                   : (BM * BK + BN * BK);
    __shared__ unsigned short smem[SMEM];
    unsigned short* As = smem;               // [BM][BK]
    unsigned short* Bs = smem + BM * BK;     // [BN][BK]

    const int tid  = threadIdx.x;
    const int w    = tid >> 6;
    const int lane = tid & 63;
    const int m0 = blockIdx.y * BM;
    const int n0 = blockIdx.x * BN;
    const int wr = (BN == 128) ? (w >> 1) * 64 : w * 32;
    const int wc = (BN == 128) ? (w & 1) * 64 : 0;

    const int srow   = lane >> 3;                          // 0..7
    const int schunk = ((lane & 7) ^ (lane >> 3)) * 8;     // swizzled k-chunk (elems)
    const int sw = lane & 7;
    const int c0 = (((lane >> 4) + 0) ^ sw) * 8;           // kk = 0 read offset
    const int c1 = (((lane >> 4) + 4) ^ sw) * 8;           // kk = 32 read offset

    f32x4 acc[MI][4] = {};

    for (int k0 = 0; k0 < K; k0 += BK) {
        __syncthreads();
#pragma unroll
        for (int t = 0; t < 4; ++t) {                      // A: 16 groups, 4/wave
            const int rbase = w * 32 + t * 8;
            const unsigned short* ga = A + (size_t)(m0 + rbase + srow) * K + k0 + schunk;
            __builtin_amdgcn_global_load_lds(
                (const __attribute__((address_space(1))) void*)ga,
                (__attribute__((address_space(3))) void*)(As + rbase * BK), 16, 0, 0);
        }
#pragma unroll
        for (int t = 0; t < BN / 32; ++t) {                // B: BN/8 groups, BN/32 per wave
            const int rbase = w * (BN / 4) + t * 8;        // FIX: wave stride = BN/4
            const unsigned short* gb = W + (size_t)(n0 + rbase + srow) * K + k0 + schunk;
            __builtin_amdgcn_global_load_lds(
                (const __attribute__((address_space(1))) void*)gb,
                (__attribute__((address_space(3))) void*)(Bs + rbase * BK), 16, 0, 0);
        }
        __syncthreads();

        const int fr = lane & 15;
#pragma unroll
        for (int kk = 0; kk < 2; ++kk) {
            const int co = kk ? c1 : c0;
            bf16x8 af[MI], bfr[4];
#pragma unroll
            for (int i = 0; i < MI; ++i)
                af[i] = *(const bf16x8*)(As + (wr + i * 16 + fr) * BK + co);
#pragma unroll
            for (int j = 0; j < 4; ++j)
                bfr[j] = *(const bf16x8*)(Bs + (wc + j * 16 + fr) * BK + co);
#pragma unroll
            for (int i = 0; i < MI; ++i)
#pragma unroll
                for (int j = 0; j < 4; ++j)
                    acc[i][j] = __builtin_amdgcn_mfma_f32_16x16x32_bf16(af[i], bfr[j], acc[i][j], 0, 0, 0);
        }
    }

    const int col = lane & 15;
    const int rq  = (lane >> 4) * 4;

    if constexpr (STORE_BF16 && BN == 128) {
        // C-tile -> LDS (stride 132, conflict-free) -> coalesced 16B stores.
        __syncthreads();   // all waves done reading As/Bs
#pragma unroll
        for (int i = 0; i < 4; ++i)
#pragma unroll
            for (int j = 0; j < 4; ++j)
#pragma unroll
                for (int r = 0; r < 4; ++r)
                    smem[(wr + i * 16 + rq + r) * LDW + wc + j * 16 + col] = f2bf(acc[i][j][r]);
        __syncthreads();
#pragma unroll
        for (int e = 0; e < 8; ++e) {
            const int idx = e * 256 + tid;      // 0..2047
            const int row = idx >> 4;           // 0..127
            const int cc  = (idx & 15) * 8;     // 0..120
            us4 lo = *(const us4*)(smem + row * LDW + cc);
            us4 hi = *(const us4*)(smem + row * LDW + cc + 4);
            us8 v;
            v[0] = lo[0]; v[1] = lo[1]; v[2] = lo[2]; v[3] = lo[3];
            v[4] = hi[0]; v[5] = hi[1]; v[6] = hi[2]; v[7] = hi[3];
            *(us8*)((unsigned short*)Cv + (size_t)(m0 + row) * N + n0 + cc) = v;
        }
    } else {
#pragma unroll
        for (int i = 0; i < MI; ++i)
#pragma unroll
            for (int j = 0; j < 4; ++j)
#pragma unroll
                for (int r = 0; r < 4; ++r) {
                    const int gm = m0 + wr + i * 16 + rq + r;
                    const int gn = n0 + wc + j * 16 + col;
                    if (STORE_BF16)
                        ((unsigned short*)Cv)[(size_t)gm * N + gn] = f2bf(acc[i][j][r]);
                    else
                        ((float*)Cv)[(size_t)gm * N + gn] = acc[i][j][r];
                }
    }
}

// ---------------------------------------------------------------------------
// MFMA sliding-window ALiBi attention (round-5 version: no post-Ps barrier,
// Ps strips are wave-private).
// ---------------------------------------------------------------------------
__global__ __launch_bounds__(256) void attn_mfma(const unsigned short* __restrict__ qkvb,
                                                 const float* __restrict__ slopes,
                                                 unsigned short* __restrict__ aoutb) {
    __shared__ unsigned short Qs[64 * LDP];
    __shared__ unsigned short Ks[64 * LDP];
    __shared__ unsigned short Vt[64 * LDP];   // [d][key]
    __shared__ unsigned short Ps[64 * LDP];   // wave-private 16-row strips

    const int tid  = threadIdx.x;
    const int w    = tid >> 6;
    const int lane = tid & 63;
    const int q0 = blockIdx.x * 64;
    const int h  = blockIdx.y;
    const int b  = blockIdx.z;
    const float slope = slopes[h];
    const size_t rowbase = (size_t)b * S_LEN * 3072;

#pragma unroll
    for (int e = 0; e < 2; ++e) {
        int idx = e * 256 + tid;
        int r = idx >> 3, cc = (idx & 7) * 8;
        us8 v = *(const us8*)(qkvb + rowbase + (size_t)(q0 + r) * 3072 + h * DK + cc);
        *(us8*)(Qs + r * LDP + cc) = v;
    }

    const int col = lane & 15;
    const int rq  = (lane >> 4) * 4;
    const int wq  = w * 16;
    const int fo  = (lane >> 4) * 8;

    f32x4 o_acc[4] = {};
    float m_i[4], l_i[4];
#pragma unroll
    for (int r = 0; r < 4; ++r) { m_i[r] = -1e30f; l_i[r] = 0.f; }

    for (int c = 0; c < 5; ++c) {
        const int k0 = q0 - 128 + c * 64;
        __syncthreads();

#pragma unroll
        for (int e = 0; e < 2; ++e) {
            int idx = e * 256 + tid;
            int r = idx >> 3, cc = (idx & 7) * 8;
            int kpos = k0 + r;
            us8 kv = {0, 0, 0, 0, 0, 0, 0, 0};
            if ((unsigned)kpos < (unsigned)S_LEN)
                kv = *(const us8*)(qkvb + rowbase + (size_t)kpos * 3072 + 1024 + h * DK + cc);
            *(us8*)(Ks + r * LDP + cc) = kv;
        }
        {
            int rp = tid >> 3;
            int cc = (tid & 7) * 8;
            int kp0 = k0 + rp * 2;
            us8 v0 = {0, 0, 0, 0, 0, 0, 0, 0}, v1 = {0, 0, 0, 0, 0, 0, 0, 0};
            if ((unsigned)kp0 < (unsigned)S_LEN)
                v0 = *(const us8*)(qkvb + rowbase + (size_t)kp0 * 3072 + 2048 + h * DK + cc);
            if ((unsigned)(kp0 + 1) < (unsigned)S_LEN)
                v1 = *(const us8*)(qkvb + rowbase + (size_t)(kp0 + 1) * 3072 + 2048 + h * DK + cc);
#pragma unroll
            for (int t = 0; t < 8; ++t) {
                unsigned pk = (unsigned)(unsigned short)v0[t] | ((unsigned)(unsigned short)v1[t] << 16);
                *(unsigned*)(Vt + (cc + t) * LDP + rp * 2) = pk;
            }
        }
        __syncthreads();

        f32x4 sacc[4] = {};
        {
            bf16x8 aq0 = *(const bf16x8*)(Qs + (wq + col) * LDP + fo);
            bf16x8 aq1 = *(const bf16x8*)(Qs + (wq + col) * LDP + fo + 32);
#pragma unroll
            for (int j = 0; j < 4; ++j) {
                bf16x8 bk0 = *(const bf16x8*)(Ks + (j * 16 + col) * LDP + fo);
                bf16x8 bk1 = *(const bf16x8*)(Ks + (j * 16 + col) * LDP + fo + 32);
                sacc[j] = __builtin_amdgcn_mfma_f32_16x16x32_bf16(aq0, bk0, sacc[j], 0, 0, 0);
                sacc[j] = __builtin_amdgcn_mfma_f32_16x16x32_bf16(aq1, bk1, sacc[j], 0, 0, 0);
            }
        }

        float sv[4][4];
#pragma unroll
        for (int j = 0; j < 4; ++j) {
            const int kpos = k0 + j * 16 + col;
            const bool kin = (unsigned)kpos < (unsigned)S_LEN;
#pragma unroll
            for (int r = 0; r < 4; ++r) {
                const int rel = (q0 + wq + rq + r) - kpos;
                const bool ok = kin && (rel <= 128) && (rel >= -128);
                sv[j][r] = ok ? (sacc[j][r] * 0.125f + slope * (float)rel) : -1e30f;
            }
        }

#pragma unroll
        for (int r = 0; r < 4; ++r) {
            float mx = fmaxf(fmaxf(sv[0][r], sv[1][r]), fmaxf(sv[2][r], sv[3][r]));
#pragma unroll
            for (int off = 1; off < 16; off <<= 1) mx = fmaxf(mx, __shfl_xor(mx, off, 64));
            const float mnew = fmaxf(m_i[r], mx);
            const float alpha = __expf(m_i[r] - mnew);
            float ps = 0.f;
#pragma unroll
            for (int j = 0; j < 4; ++j) {
                float p = (sv[j][r] < -9e29f) ? 0.f : __expf(sv[j][r] - mnew);
                sv[j][r] = p;
                ps += p;
            }
#pragma unroll
            for (int off = 1; off < 16; off <<= 1) ps += __shfl_xor(ps, off, 64);
            l_i[r] = l_i[r] * alpha + ps;
            m_i[r] = mnew;
#pragma unroll
            for (int j = 0; j < 4; ++j) o_acc[j][r] *= alpha;
        }

#pragma unroll
        for (int j = 0; j < 4; ++j)
#pragma unroll
            for (int r = 0; r < 4; ++r)
                Ps[(wq + rq + r) * LDP + j * 16 + col] = f2bf(sv[j][r]);
        // no barrier: Ps rows [wq, wq+16) are written and read by this wave only

        {
            bf16x8 ap0 = *(const bf16x8*)(Ps + (wq + col) * LDP + fo);
            bf16x8 ap1 = *(const bf16x8*)(Ps + (wq + col) * LDP + fo + 32);
#pragma unroll
            for (int j = 0; j < 4; ++j) {
                bf16x8 bv0 = *(const bf16x8*)(Vt + (j * 16 + col) * LDP + fo);
                bf16x8 bv1 = *(const bf16x8*)(Vt + (j * 16 + col) * LDP + fo + 32);
                o_acc[j] = __builtin_amdgcn_mfma_f32_16x16x32_bf16(ap0, bv0, o_acc[j], 0, 0, 0);
                o_acc[j] = __builtin_amdgcn_mfma_f32_16x16x32_bf16(ap1, bv1, o_acc[j], 0, 0, 0);
            }
        }
    }

    float inv[4];
#pragma unroll
    for (int r = 0; r < 4; ++r) inv[r] = 1.f / l_i[r];
#pragma unroll
    for (int j = 0; j < 4; ++j)
#pragma unroll
        for (int r = 0; r < 4; ++r) {
            const int qpos = q0 + wq + rq + r;
            aoutb[((size_t)b * S_LEN + qpos) * D_MODEL + h * DK + j * 16 + col] =
                f2bf(o_acc[j][r] * inv[r]);
        }
}

// ---------------------------------------------------------------------------
extern "C" void kernel_launch(void* const* d_in, const int* in_sizes, int n_in,
                              void* d_out, int out_size, void* d_ws, size_t ws_size,
                              hipStream_t stream) {
    const float* x      = (const float*)d_in[0];
    const float* Wq     = (const float*)d_in[1];
    const float* Wk     = (const float*)d_in[2];
    const float* Wv     = (const float*)d_in[3];
    const float* Wo     = (const float*)d_in[4];
    const float* slopes = (const float*)d_in[5];
    float* out = (float*)d_out;

    unsigned short* xb    = (unsigned short*)d_ws;            // [4096,1024]
    unsigned short* wb    = xb    + (size_t)M_ROWS * D_MODEL; // [3072,1024] Wq|Wk|Wv
    unsigned short* wob   = wb    + (size_t)3072 * D_MODEL;   // [1024,1024]
    unsigned short* qkvb  = wob   + (size_t)1024 * D_MODEL;   // [4096,3072]
    unsigned short* aoutb = qkvb  + (size_t)M_ROWS * 3072;    // [4096,1024]

    dim3 blk(256);
    cvt_all<<<4096, blk, 0, stream>>>(x, Wq, Wk, Wv, Wo, xb);
    mfma_gemm_bt<1, 128><<<dim3(3072 / 128, M_ROWS / 128), blk, 0, stream>>>(xb, wb, qkvb, 3072);
    attn_mfma<<<dim3(S_LEN / 64, NH, BATCH), blk, 0, stream>>>(qkvb, slopes, aoutb);
    mfma_gemm_bt<0, 64><<<dim3(1024 / 64, M_ROWS / 128), blk, 0, stream>>>(aoutb, wob, out, 1024);
}